// Round 1
// baseline (1344.301 us; speedup 1.0000x reference)
//
#include <hip/hip_runtime.h>
#include <math.h>

// ---------------- degree / norm ----------------

__global__ void count_dst_kernel(const int* __restrict__ dst, int E, int* __restrict__ cnt) {
    int e = blockIdx.x * blockDim.x + threadIdx.x;
    if (e < E) atomicAdd(&cnt[dst[e]], 1);
}

__global__ void dinv_kernel(const int* __restrict__ cnt, float* __restrict__ dinv, int N) {
    int v = blockIdx.x * blockDim.x + threadIdx.x;
    if (v < N) {
        float d = (float)(cnt[v] + 1);   // +1 self loop; always >= 1
        dinv[v] = rsqrtf(d);
    }
}

// ---------------- exclusive scan (3-kernel, CHUNK=1024) ----------------

__global__ void scan1_kernel(const int* __restrict__ cnt, int N,
                             int* __restrict__ offs, int* __restrict__ partials) {
    __shared__ int sd[256];
    int b = blockIdx.x, t = threadIdx.x;
    int base = b * 1024 + t * 4;
    int v[4]; int s = 0;
#pragma unroll
    for (int i = 0; i < 4; ++i) { v[i] = (base + i < N) ? cnt[base + i] : 0; s += v[i]; }
    sd[t] = s; __syncthreads();
    for (int d = 1; d < 256; d <<= 1) {
        int x = (t >= d) ? sd[t - d] : 0;
        __syncthreads();
        sd[t] += x;
        __syncthreads();
    }
    int p = sd[t] - s;   // exclusive prefix within chunk
#pragma unroll
    for (int i = 0; i < 4; ++i) { if (base + i < N) offs[base + i] = p; p += v[i]; }
    if (t == 255) partials[b] = sd[255];
}

__global__ void scan2_kernel(int* partials, int nb) {
    __shared__ int sd[256];
    int t = threadIdx.x;
    int v = (t < nb) ? partials[t] : 0;
    sd[t] = v; __syncthreads();
    for (int d = 1; d < 256; d <<= 1) {
        int x = (t >= d) ? sd[t - d] : 0;
        __syncthreads();
        sd[t] += x;
        __syncthreads();
    }
    if (t < nb) partials[t] = sd[t] - v;  // exclusive
}

__global__ void scan3_kernel(int* __restrict__ offs, int* __restrict__ cur,
                             const int* __restrict__ partials, int N) {
    int i = blockIdx.x * blockDim.x + threadIdx.x;
    if (i < N) {
        int o = offs[i] + partials[i >> 10];
        offs[i] = o; cur[i] = o;
    }
}

__global__ void scatter_kernel(const int* __restrict__ src, const int* __restrict__ dst, int E,
                               int* __restrict__ cur, int* __restrict__ csr) {
    int e = blockIdx.x * blockDim.x + threadIdx.x;
    if (e < E) {
        int pos = atomicAdd(&cur[dst[e]], 1);
        csr[pos] = src[e];
    }
}

// ---------------- fp32 GEMM:  C[M,128] = A[M,K] @ W[K,128] ----------------
// block 256 thr, tile BM=128 x BN=128 x BK=32; thread tile 8x8 (rows interleaved by 16)

__global__ __launch_bounds__(256) void gemm_kernel(const float* __restrict__ A,
                                                   const float* __restrict__ W,
                                                   float* __restrict__ C, int M, int K) {
    __shared__ float Xs[128][33];
    __shared__ float Ws[32][128];
    int t = threadIdx.x;
    int row0 = blockIdx.x * 128;
    int rg = t & 15;        // 16 row groups -> rows rg + 16*r (conflict-free LDS reads)
    int cg = t >> 4;        // 16 col groups -> cols cg*8 .. +7
    int c_base = cg * 8;

    float acc[8][8];
#pragma unroll
    for (int r = 0; r < 8; ++r)
#pragma unroll
        for (int c = 0; c < 8; ++c) acc[r][c] = 0.f;

    for (int k0 = 0; k0 < K; k0 += 32) {
        // stage A tile: 128x32 floats (1024 float4, 4 per thread)
#pragma unroll
        for (int i = 0; i < 4; ++i) {
            int idx = t + i * 256;
            int r = idx >> 3;
            int c4 = (idx & 7) * 4;
            float4 v = {0.f, 0.f, 0.f, 0.f};
            int gr = row0 + r;
            if (gr < M) v = *(const float4*)(A + (size_t)gr * K + k0 + c4);
            Xs[r][c4 + 0] = v.x; Xs[r][c4 + 1] = v.y;
            Xs[r][c4 + 2] = v.z; Xs[r][c4 + 3] = v.w;
        }
        // stage W tile: 32x128 floats
#pragma unroll
        for (int i = 0; i < 4; ++i) {
            int idx = t + i * 256;
            int r = idx >> 5;
            int c4 = (idx & 31) * 4;
            *(float4*)&Ws[r][c4] = *(const float4*)(W + (size_t)(k0 + r) * 128 + c4);
        }
        __syncthreads();
#pragma unroll
        for (int kk = 0; kk < 32; ++kk) {
            float4 w0 = *(const float4*)&Ws[kk][c_base];
            float4 w1 = *(const float4*)&Ws[kk][c_base + 4];
            float xr[8];
#pragma unroll
            for (int r = 0; r < 8; ++r) xr[r] = Xs[rg + 16 * r][kk];
#pragma unroll
            for (int r = 0; r < 8; ++r) {
                acc[r][0] += xr[r] * w0.x; acc[r][1] += xr[r] * w0.y;
                acc[r][2] += xr[r] * w0.z; acc[r][3] += xr[r] * w0.w;
                acc[r][4] += xr[r] * w1.x; acc[r][5] += xr[r] * w1.y;
                acc[r][6] += xr[r] * w1.z; acc[r][7] += xr[r] * w1.w;
            }
        }
        __syncthreads();
    }
#pragma unroll
    for (int r = 0; r < 8; ++r) {
        int gr = row0 + rg + 16 * r;
        if (gr < M) {
            float4 o0 = {acc[r][0], acc[r][1], acc[r][2], acc[r][3]};
            float4 o1 = {acc[r][4], acc[r][5], acc[r][6], acc[r][7]};
            *(float4*)(C + (size_t)gr * 128 + c_base) = o0;
            *(float4*)(C + (size_t)gr * 128 + c_base + 4) = o1;
        }
    }
}

// ---------------- aggregation: one wave per output row ----------------
// out_row = dinv[v] * ( sum_{e: dst=v} dinv[src]*xw[src] + dinv[v]*xw[v] ) + bias, then ELU

__global__ __launch_bounds__(256) void agg_kernel(const float* __restrict__ xw,
                                                  const int* __restrict__ csr,
                                                  const int* __restrict__ offs,
                                                  const int* __restrict__ cnt,
                                                  const float* __restrict__ dinv,
                                                  const float* __restrict__ bias,
                                                  const int* __restrict__ nodelist, int nwork,
                                                  float* __restrict__ out, int out_stride,
                                                  int out_col0) {
    int wid = (blockIdx.x * blockDim.x + threadIdx.x) >> 6;
    if (wid >= nwork) return;
    int lane = threadIdx.x & 63;
    int v = nodelist ? nodelist[wid] : wid;
    int o = offs[v];
    int c = cnt[v];
    float dv = dinv[v];
    float ax = 0.f, ay = 0.f;

    for (int base = 0; base < c; base += 64) {
        int rem = c - base; if (rem > 64) rem = 64;
        int li = base + lane; if (li >= c) li = c - 1;
        int s_l = csr[o + li];
        float d_l = dinv[s_l];
        int j = 0;
        for (; j + 4 <= rem; j += 4) {
            int s0 = __shfl(s_l, j);     int s1 = __shfl(s_l, j + 1);
            int s2 = __shfl(s_l, j + 2); int s3 = __shfl(s_l, j + 3);
            float e0 = __shfl(d_l, j);     float e1 = __shfl(d_l, j + 1);
            float e2 = __shfl(d_l, j + 2); float e3 = __shfl(d_l, j + 3);
            float2 v0 = *(const float2*)(xw + (size_t)s0 * 128 + lane * 2);
            float2 v1 = *(const float2*)(xw + (size_t)s1 * 128 + lane * 2);
            float2 v2 = *(const float2*)(xw + (size_t)s2 * 128 + lane * 2);
            float2 v3 = *(const float2*)(xw + (size_t)s3 * 128 + lane * 2);
            ax += e0 * v0.x + e1 * v1.x + e2 * v2.x + e3 * v3.x;
            ay += e0 * v0.y + e1 * v1.y + e2 * v2.y + e3 * v3.y;
        }
        for (; j < rem; ++j) {
            int s = __shfl(s_l, j);
            float e = __shfl(d_l, j);
            float2 vv = *(const float2*)(xw + (size_t)s * 128 + lane * 2);
            ax += e * vv.x; ay += e * vv.y;
        }
    }
    // self loop
    float2 sv = *(const float2*)(xw + (size_t)v * 128 + lane * 2);
    ax += dv * sv.x; ay += dv * sv.y;
    ax = dv * ax + bias[lane * 2];
    ay = dv * ay + bias[lane * 2 + 1];
    ax = ax > 0.f ? ax : expm1f(ax);
    ay = ay > 0.f ? ay : expm1f(ay);
    float2 res = {ax, ay};
    *(float2*)(out + (size_t)wid * out_stride + out_col0 + lane * 2) = res;
}

// ---------------- head: logits + log_softmax over 2048 roots ----------------

__global__ __launch_bounds__(256) void head_kernel(const float* __restrict__ feat,
                                                   const float* __restrict__ fcw,
                                                   const float* __restrict__ fcb,
                                                   float* __restrict__ out, int R) {
    int wid = (blockIdx.x * blockDim.x + threadIdx.x) >> 6;
    if (wid >= R) return;
    int lane = threadIdx.x & 63;
    const float* fr = feat + (size_t)wid * 256;
    float a0 = 0.f, a1 = 0.f, a2 = 0.f, a3 = 0.f;
    for (int k = lane; k < 256; k += 64) {
        float f = fr[k];
        float4 w = *(const float4*)(fcw + k * 4);
        a0 += f * w.x; a1 += f * w.y; a2 += f * w.z; a3 += f * w.w;
    }
#pragma unroll
    for (int d = 1; d < 64; d <<= 1) {
        a0 += __shfl_xor(a0, d); a1 += __shfl_xor(a1, d);
        a2 += __shfl_xor(a2, d); a3 += __shfl_xor(a3, d);
    }
    if (lane == 0) {
        a0 += fcb[0]; a1 += fcb[1]; a2 += fcb[2]; a3 += fcb[3];
        float m = fmaxf(fmaxf(a0, a1), fmaxf(a2, a3));
        float s = expf(a0 - m) + expf(a1 - m) + expf(a2 - m) + expf(a3 - m);
        float ls = logf(s) + m;
        float4 r = {a0 - ls, a1 - ls, a2 - ls, a3 - ls};
        *(float4*)(out + (size_t)wid * 4) = r;
    }
}

// ---------------- launch ----------------

extern "C" void kernel_launch(void* const* d_in, const int* in_sizes, int n_in,
                              void* d_out, int out_size, void* d_ws, size_t ws_size,
                              hipStream_t stream) {
    const float* x    = (const float*)d_in[0];
    const int*   ei   = (const int*)d_in[1];
    const int*   bei  = (const int*)d_in[2];
    const int*   roots= (const int*)d_in[3];
    const float* w1 = (const float*)d_in[4];
    const float* b1 = (const float*)d_in[5];
    const float* w2 = (const float*)d_in[6];
    const float* b2 = (const float*)d_in[7];
    const float* w3 = (const float*)d_in[8];
    const float* b3 = (const float*)d_in[9];
    const float* w4 = (const float*)d_in[10];
    const float* b4 = (const float*)d_in[11];
    const float* fcw = (const float*)d_in[12];
    const float* fcb = (const float*)d_in[13];
    float* out = (float*)d_out;

    const int N = in_sizes[0] / 256;
    const int E = in_sizes[1] / 2;
    const int R = in_sizes[3];

    char* ws = (char*)d_ws;
    size_t off = 0;
    auto alloc = [&](size_t b) { size_t o = off; off += (b + 255) & ~(size_t)255; return o; };
    float* xw   = (float*)(ws + alloc((size_t)N * 128 * 4));
    float* h    = (float*)(ws + alloc((size_t)N * 128 * 4));
    int*   csr  = (int*)(ws + alloc((size_t)E * 4));
    int*   cnt  = (int*)(ws + alloc((size_t)N * 4));
    int*   offs = (int*)(ws + alloc((size_t)N * 4));
    int*   cur  = (int*)(ws + alloc((size_t)N * 4));
    float* dinv = (float*)(ws + alloc((size_t)N * 4));
    float* feat = (float*)(ws + alloc((size_t)R * 256 * 4));
    int*   partials = (int*)(ws + alloc(1024));

    const int nchunks = (N + 1023) / 1024;

    for (int br = 0; br < 2; ++br) {
        const int* e   = (br == 0) ? ei : bei;
        const int* srcp = e;
        const int* dstp = e + E;
        const float* wA = (br == 0) ? w1 : w3;
        const float* bA = (br == 0) ? b1 : b3;
        const float* wB = (br == 0) ? w2 : w4;
        const float* bB = (br == 0) ? b2 : b4;

        hipMemsetAsync(cnt, 0, (size_t)N * 4, stream);
        count_dst_kernel<<<(E + 255) / 256, 256, 0, stream>>>(dstp, E, cnt);
        dinv_kernel<<<(N + 255) / 256, 256, 0, stream>>>(cnt, dinv, N);
        scan1_kernel<<<nchunks, 256, 0, stream>>>(cnt, N, offs, partials);
        scan2_kernel<<<1, 256, 0, stream>>>(partials, nchunks);
        scan3_kernel<<<(N + 255) / 256, 256, 0, stream>>>(offs, cur, partials, N);
        scatter_kernel<<<(E + 255) / 256, 256, 0, stream>>>(srcp, dstp, E, cur, csr);

        // layer 1: full aggregation (h needed at all nodes for layer-2 GEMM)
        gemm_kernel<<<(N + 127) / 128, 256, 0, stream>>>(x, wA, xw, N, 256);
        agg_kernel<<<((size_t)N * 64 + 255) / 256, 256, 0, stream>>>(
            xw, csr, offs, cnt, dinv, bA, nullptr, N, h, 128, 0);
        // layer 2: aggregation only at root nodes
        gemm_kernel<<<(N + 127) / 128, 256, 0, stream>>>(h, wB, xw, N, 128);
        agg_kernel<<<((size_t)R * 64 + 255) / 256, 256, 0, stream>>>(
            xw, csr, offs, cnt, dinv, bB, roots, R, feat, 256, br * 128);
    }
    head_kernel<<<((size_t)R * 64 + 255) / 256, 256, 0, stream>>>(feat, fcw, fcb, out, R);
}

// Round 2
// 978.598 us; speedup vs baseline: 1.3737x; 1.3737x over previous
//
#include <hip/hip_runtime.h>
#include <math.h>

typedef __attribute__((ext_vector_type(8))) short short8v;
typedef __attribute__((ext_vector_type(4))) float float4v;
typedef __attribute__((ext_vector_type(4))) unsigned short ushort4v;
typedef __attribute__((ext_vector_type(8))) unsigned short ushort8v;

__device__ inline unsigned short f2bf(float f) {
    unsigned u = __float_as_uint(f);
    return (unsigned short)((u + 0x7FFFu + ((u >> 16) & 1u)) >> 16);
}

// ---------------- degree / norm ----------------

__global__ void count_dst_kernel(const int* __restrict__ dst, int E, int* __restrict__ cnt) {
    int e = blockIdx.x * blockDim.x + threadIdx.x;
    if (e < E) atomicAdd(&cnt[dst[e]], 1);
}

__global__ void dinv_kernel(const int* __restrict__ cnt, float* __restrict__ dinv, int N) {
    int v = blockIdx.x * blockDim.x + threadIdx.x;
    if (v < N) {
        float d = (float)(cnt[v] + 1);   // +1 self loop; always >= 1
        dinv[v] = rsqrtf(d);
    }
}

// ---------------- exclusive scan (3-kernel, CHUNK=1024) ----------------

__global__ void scan1_kernel(const int* __restrict__ cnt, int N,
                             int* __restrict__ offs, int* __restrict__ partials) {
    __shared__ int sd[256];
    int b = blockIdx.x, t = threadIdx.x;
    int base = b * 1024 + t * 4;
    int v[4]; int s = 0;
#pragma unroll
    for (int i = 0; i < 4; ++i) { v[i] = (base + i < N) ? cnt[base + i] : 0; s += v[i]; }
    sd[t] = s; __syncthreads();
    for (int d = 1; d < 256; d <<= 1) {
        int x = (t >= d) ? sd[t - d] : 0;
        __syncthreads();
        sd[t] += x;
        __syncthreads();
    }
    int p = sd[t] - s;   // exclusive prefix within chunk
#pragma unroll
    for (int i = 0; i < 4; ++i) { if (base + i < N) offs[base + i] = p; p += v[i]; }
    if (t == 255) partials[b] = sd[255];
}

__global__ void scan2_kernel(int* partials, int nb) {
    __shared__ int sd[256];
    int t = threadIdx.x;
    int v = (t < nb) ? partials[t] : 0;
    sd[t] = v; __syncthreads();
    for (int d = 1; d < 256; d <<= 1) {
        int x = (t >= d) ? sd[t - d] : 0;
        __syncthreads();
        sd[t] += x;
        __syncthreads();
    }
    if (t < nb) partials[t] = sd[t] - v;  // exclusive
}

__global__ void scan3_kernel(int* __restrict__ offs, int* __restrict__ cur,
                             const int* __restrict__ partials, int N) {
    int i = blockIdx.x * blockDim.x + threadIdx.x;
    if (i < N) {
        int o = offs[i] + partials[i >> 10];
        offs[i] = o; cur[i] = o;
    }
}

__global__ void scatter_kernel(const int* __restrict__ src, const int* __restrict__ dst, int E,
                               int* __restrict__ cur, int* __restrict__ csr) {
    int e = blockIdx.x * blockDim.x + threadIdx.x;
    if (e < E) {
        int pos = atomicAdd(&cur[dst[e]], 1);
        csr[pos] = src[e];
    }
}

// ---------------- W split: W[K,128] fp32 -> WThi/WTlo[128][K] bf16 ----------------

__global__ void wsplit_kernel(const float* __restrict__ W, int K,
                              unsigned short* __restrict__ WThi,
                              unsigned short* __restrict__ WTlo) {
    int i = blockIdx.x * blockDim.x + threadIdx.x;
    if (i >= K * 128) return;
    int k = i >> 7, c = i & 127;
    float w = W[i];
    unsigned short h = f2bf(w);
    float hf = __uint_as_float((unsigned)h << 16);
    WThi[(size_t)c * K + k] = h;
    WTlo[(size_t)c * K + k] = f2bf(w - hf);
}

// ---------------- split-bf16 MFMA GEMM: C[M,128] = A[M,K] @ W[K,128] ----------------
// A fp32 converted to hi/lo bf16 inline during LDS staging.
// C = Ah*Bh + Ah*Bl + Al*Bh  (lo*lo dropped; ~2^-17 relative error)
// Block: 256 thr = 4 waves; tile 128x128, BK=32. Wave w owns rows w*32..w*32+31.

__global__ __launch_bounds__(256) void gemm_mfma_kernel(const float* __restrict__ A,
                                                        const unsigned short* __restrict__ WThi,
                                                        const unsigned short* __restrict__ WTlo,
                                                        float* __restrict__ C, int M, int K) {
    __shared__ unsigned short Ah[128 * 32];
    __shared__ unsigned short Al[128 * 32];
    __shared__ unsigned short Bh[128 * 32];
    __shared__ unsigned short Bl[128 * 32];
    int t = threadIdx.x;
    int w = t >> 6, l = t & 63;
    int lr = l & 15, lk = l >> 4;     // frag row/col, k-block
    int row0 = blockIdx.x * 128;

    float4v acc[2][8];
#pragma unroll
    for (int mf = 0; mf < 2; ++mf)
#pragma unroll
        for (int nf = 0; nf < 8; ++nf) acc[mf][nf] = (float4v){0.f, 0.f, 0.f, 0.f};

    for (int k0 = 0; k0 < K; k0 += 32) {
        // stage A tile 128x32 fp32 -> hi/lo bf16 (1024 float4 loads, 4/thread)
#pragma unroll
        for (int i = 0; i < 4; ++i) {
            int idx = t + i * 256;
            int r = idx >> 3, c4 = (idx & 7) * 4;
            int gr = row0 + r;
            float4 v = {0.f, 0.f, 0.f, 0.f};
            if (gr < M) v = *(const float4*)(A + (size_t)gr * K + k0 + c4);
            float fs[4] = {v.x, v.y, v.z, v.w};
            ushort4v hi, lo;
#pragma unroll
            for (int j = 0; j < 4; ++j) {
                unsigned short h = f2bf(fs[j]);
                float hf = __uint_as_float((unsigned)h << 16);
                hi[j] = h;
                lo[j] = f2bf(fs[j] - hf);
            }
            *(ushort4v*)&Ah[r * 32 + c4] = hi;
            *(ushort4v*)&Al[r * 32 + c4] = lo;
        }
        // stage B tile: WT[128][K] slice cols k0..k0+31 (already transposed/split)
#pragma unroll
        for (int i = 0; i < 2; ++i) {
            int cidx = t + i * 256;          // 0..511, 16B chunks
            int col = cidx >> 2, q = cidx & 3;
            ushort8v vh = *(const ushort8v*)(WThi + (size_t)col * K + k0 + q * 8);
            ushort8v vl = *(const ushort8v*)(WTlo + (size_t)col * K + k0 + q * 8);
            *(ushort8v*)&Bh[col * 32 + q * 8] = vh;
            *(ushort8v*)&Bl[col * 32 + q * 8] = vl;
        }
        __syncthreads();

        short8v ah0 = *(const short8v*)&Ah[(w * 32 + lr) * 32 + lk * 8];
        short8v al0 = *(const short8v*)&Al[(w * 32 + lr) * 32 + lk * 8];
        short8v ah1 = *(const short8v*)&Ah[(w * 32 + 16 + lr) * 32 + lk * 8];
        short8v al1 = *(const short8v*)&Al[(w * 32 + 16 + lr) * 32 + lk * 8];
#pragma unroll
        for (int nf = 0; nf < 8; ++nf) {
            short8v bh = *(const short8v*)&Bh[(nf * 16 + lr) * 32 + lk * 8];
            short8v bl = *(const short8v*)&Bl[(nf * 16 + lr) * 32 + lk * 8];
            acc[0][nf] = __builtin_amdgcn_mfma_f32_16x16x32_bf16(ah0, bh, acc[0][nf], 0, 0, 0);
            acc[0][nf] = __builtin_amdgcn_mfma_f32_16x16x32_bf16(ah0, bl, acc[0][nf], 0, 0, 0);
            acc[0][nf] = __builtin_amdgcn_mfma_f32_16x16x32_bf16(al0, bh, acc[0][nf], 0, 0, 0);
            acc[1][nf] = __builtin_amdgcn_mfma_f32_16x16x32_bf16(ah1, bh, acc[1][nf], 0, 0, 0);
            acc[1][nf] = __builtin_amdgcn_mfma_f32_16x16x32_bf16(ah1, bl, acc[1][nf], 0, 0, 0);
            acc[1][nf] = __builtin_amdgcn_mfma_f32_16x16x32_bf16(al1, bh, acc[1][nf], 0, 0, 0);
        }
        __syncthreads();
    }
    // store: D row = lk*4 + r, col = lr (m89-verified C/D mapping)
#pragma unroll
    for (int mf = 0; mf < 2; ++mf)
#pragma unroll
        for (int nf = 0; nf < 8; ++nf)
#pragma unroll
            for (int r = 0; r < 4; ++r) {
                int grow = row0 + w * 32 + mf * 16 + lk * 4 + r;
                if (grow < M) C[(size_t)grow * 128 + nf * 16 + lr] = acc[mf][nf][r];
            }
}

// ---------------- aggregation: one wave per output row ----------------
// out_row = dinv[v] * ( sum_{e: dst=v} dinv[src]*xw[src] + dinv[v]*xw[v] ) + bias, then ELU

__global__ __launch_bounds__(256) void agg_kernel(const float* __restrict__ xw,
                                                  const int* __restrict__ csr,
                                                  const int* __restrict__ offs,
                                                  const int* __restrict__ cnt,
                                                  const float* __restrict__ dinv,
                                                  const float* __restrict__ bias,
                                                  const int* __restrict__ nodelist, int nwork,
                                                  float* __restrict__ out, int out_stride,
                                                  int out_col0) {
    int wid = (blockIdx.x * blockDim.x + threadIdx.x) >> 6;
    if (wid >= nwork) return;
    int lane = threadIdx.x & 63;
    int v = nodelist ? nodelist[wid] : wid;
    int o = offs[v];
    int c = cnt[v];
    float dv = dinv[v];
    float ax = 0.f, ay = 0.f;

    for (int base = 0; base < c; base += 64) {
        int rem = c - base; if (rem > 64) rem = 64;
        int li = base + lane; if (li >= c) li = c - 1;
        int s_l = csr[o + li];
        float d_l = dinv[s_l];
        int j = 0;
        for (; j + 4 <= rem; j += 4) {
            int s0 = __shfl(s_l, j);     int s1 = __shfl(s_l, j + 1);
            int s2 = __shfl(s_l, j + 2); int s3 = __shfl(s_l, j + 3);
            float e0 = __shfl(d_l, j);     float e1 = __shfl(d_l, j + 1);
            float e2 = __shfl(d_l, j + 2); float e3 = __shfl(d_l, j + 3);
            float2 v0 = *(const float2*)(xw + (size_t)s0 * 128 + lane * 2);
            float2 v1 = *(const float2*)(xw + (size_t)s1 * 128 + lane * 2);
            float2 v2 = *(const float2*)(xw + (size_t)s2 * 128 + lane * 2);
            float2 v3 = *(const float2*)(xw + (size_t)s3 * 128 + lane * 2);
            ax += e0 * v0.x + e1 * v1.x + e2 * v2.x + e3 * v3.x;
            ay += e0 * v0.y + e1 * v1.y + e2 * v2.y + e3 * v3.y;
        }
        for (; j < rem; ++j) {
            int s = __shfl(s_l, j);
            float e = __shfl(d_l, j);
            float2 vv = *(const float2*)(xw + (size_t)s * 128 + lane * 2);
            ax += e * vv.x; ay += e * vv.y;
        }
    }
    // self loop
    float2 sv = *(const float2*)(xw + (size_t)v * 128 + lane * 2);
    ax += dv * sv.x; ay += dv * sv.y;
    ax = dv * ax + bias[lane * 2];
    ay = dv * ay + bias[lane * 2 + 1];
    ax = ax > 0.f ? ax : expm1f(ax);
    ay = ay > 0.f ? ay : expm1f(ay);
    float2 res = {ax, ay};
    *(float2*)(out + (size_t)wid * out_stride + out_col0 + lane * 2) = res;
}

// ---------------- head: logits + log_softmax over 2048 roots ----------------

__global__ __launch_bounds__(256) void head_kernel(const float* __restrict__ feat,
                                                   const float* __restrict__ fcw,
                                                   const float* __restrict__ fcb,
                                                   float* __restrict__ out, int R) {
    int wid = (blockIdx.x * blockDim.x + threadIdx.x) >> 6;
    if (wid >= R) return;
    int lane = threadIdx.x & 63;
    const float* fr = feat + (size_t)wid * 256;
    float a0 = 0.f, a1 = 0.f, a2 = 0.f, a3 = 0.f;
    for (int k = lane; k < 256; k += 64) {
        float f = fr[k];
        float4 w = *(const float4*)(fcw + k * 4);
        a0 += f * w.x; a1 += f * w.y; a2 += f * w.z; a3 += f * w.w;
    }
#pragma unroll
    for (int d = 1; d < 64; d <<= 1) {
        a0 += __shfl_xor(a0, d); a1 += __shfl_xor(a1, d);
        a2 += __shfl_xor(a2, d); a3 += __shfl_xor(a3, d);
    }
    if (lane == 0) {
        a0 += fcb[0]; a1 += fcb[1]; a2 += fcb[2]; a3 += fcb[3];
        float m = fmaxf(fmaxf(a0, a1), fmaxf(a2, a3));
        float s = expf(a0 - m) + expf(a1 - m) + expf(a2 - m) + expf(a3 - m);
        float ls = logf(s) + m;
        float4 r = {a0 - ls, a1 - ls, a2 - ls, a3 - ls};
        *(float4*)(out + (size_t)wid * 4) = r;
    }
}

// ---------------- launch ----------------

extern "C" void kernel_launch(void* const* d_in, const int* in_sizes, int n_in,
                              void* d_out, int out_size, void* d_ws, size_t ws_size,
                              hipStream_t stream) {
    const float* x    = (const float*)d_in[0];
    const int*   ei   = (const int*)d_in[1];
    const int*   bei  = (const int*)d_in[2];
    const int*   roots= (const int*)d_in[3];
    const float* w1 = (const float*)d_in[4];
    const float* b1 = (const float*)d_in[5];
    const float* w2 = (const float*)d_in[6];
    const float* b2 = (const float*)d_in[7];
    const float* w3 = (const float*)d_in[8];
    const float* b3 = (const float*)d_in[9];
    const float* w4 = (const float*)d_in[10];
    const float* b4 = (const float*)d_in[11];
    const float* fcw = (const float*)d_in[12];
    const float* fcb = (const float*)d_in[13];
    float* out = (float*)d_out;

    const int N = in_sizes[0] / 256;
    const int E = in_sizes[1] / 2;
    const int R = in_sizes[3];

    char* ws = (char*)d_ws;
    size_t off = 0;
    auto alloc = [&](size_t b) { size_t o = off; off += (b + 255) & ~(size_t)255; return o; };
    float* xw   = (float*)(ws + alloc((size_t)N * 128 * 4));
    float* h    = (float*)(ws + alloc((size_t)N * 128 * 4));
    int*   csr  = (int*)(ws + alloc((size_t)E * 4));
    int*   cnt  = (int*)(ws + alloc((size_t)N * 4));
    int*   offs = (int*)(ws + alloc((size_t)N * 4));
    int*   cur  = (int*)(ws + alloc((size_t)N * 4));
    float* dinv = (float*)(ws + alloc((size_t)N * 4));
    float* feat = (float*)(ws + alloc((size_t)R * 256 * 4));
    int*   partials = (int*)(ws + alloc(1024));
    unsigned short* WThi = (unsigned short*)(ws + alloc((size_t)128 * 256 * 2));
    unsigned short* WTlo = (unsigned short*)(ws + alloc((size_t)128 * 256 * 2));

    const int nchunks = (N + 1023) / 1024;

    for (int br = 0; br < 2; ++br) {
        const int* e   = (br == 0) ? ei : bei;
        const int* srcp = e;
        const int* dstp = e + E;
        const float* wA = (br == 0) ? w1 : w3;
        const float* bA = (br == 0) ? b1 : b3;
        const float* wB = (br == 0) ? w2 : w4;
        const float* bB = (br == 0) ? b2 : b4;

        hipMemsetAsync(cnt, 0, (size_t)N * 4, stream);
        count_dst_kernel<<<(E + 255) / 256, 256, 0, stream>>>(dstp, E, cnt);
        dinv_kernel<<<(N + 255) / 256, 256, 0, stream>>>(cnt, dinv, N);
        scan1_kernel<<<nchunks, 256, 0, stream>>>(cnt, N, offs, partials);
        scan2_kernel<<<1, 256, 0, stream>>>(partials, nchunks);
        scan3_kernel<<<(N + 255) / 256, 256, 0, stream>>>(offs, cur, partials, N);
        scatter_kernel<<<(E + 255) / 256, 256, 0, stream>>>(srcp, dstp, E, cur, csr);

        // layer 1: full aggregation (h needed at all nodes for layer-2 GEMM)
        wsplit_kernel<<<(256 * 128 + 255) / 256, 256, 0, stream>>>(wA, 256, WThi, WTlo);
        gemm_mfma_kernel<<<(N + 127) / 128, 256, 0, stream>>>(x, WThi, WTlo, xw, N, 256);
        agg_kernel<<<((size_t)N * 64 + 255) / 256, 256, 0, stream>>>(
            xw, csr, offs, cnt, dinv, bA, nullptr, N, h, 128, 0);
        // layer 2: aggregation only at root nodes
        wsplit_kernel<<<(128 * 128 + 255) / 256, 256, 0, stream>>>(wB, 128, WThi, WTlo);
        gemm_mfma_kernel<<<(N + 127) / 128, 256, 0, stream>>>(h, WThi, WTlo, xw, N, 128);
        agg_kernel<<<((size_t)R * 64 + 255) / 256, 256, 0, stream>>>(
            xw, csr, offs, cnt, dinv, bB, roots, R, feat, 256, br * 128);
    }
    head_kernel<<<((size_t)R * 64 + 255) / 256, 256, 0, stream>>>(feat, fcw, fcb, out, R);
}